// Round 10
// baseline (186.257 us; speedup 1.0000x reference)
//
#include <hip/hip_runtime.h>

// COO SpMM: out[row[e], :] += values[e] * b[col[e], :]   (d = 128, f32)
//
// Round 10: TLP-max k4. RPB=32, 128-thread blocks (2 waves x 16 rows):
//  - NB=3125 blocks; 16 blocks/CU (thread-limited), LDS 8.3KB -> all blocks
//    resident in ONE generation, 32 waves/CU theoretical occupancy.
//  - depth-2 x 8-wide pipeline kept (VGPR ~48 <= 64 keeps 8 waves/SIMD).
//  - pad-to-8 rows; {col_off=0, val=0} pads gather b[0] and contribute 0.
// k1/k3 take MAXNB=4096; k2 scan handles NB<=4096 (4 elems/thread).

#define DIM 128
#define RPB 32          // rows per bucket
#define BLK 128         // k4 block size (2 waves)
#define STAGE 768       // max real edges staged (mean 512, +11 sigma) = 6*128
#define CAP (STAGE + 7 * RPB)   // 992: worst-case pad-to-8
#define NCH 256         // chunk-blocks for count/partition
#define MAXNB 4096

// ---------------- fallback: edge-parallel atomics ----------------
__global__ __launch_bounds__(256) void spmm_atomic_kernel(
    const int* __restrict__ rows, const int* __restrict__ cols,
    const float* __restrict__ vals, const float* __restrict__ b,
    float* __restrict__ out, int E)
{
    long long t = (long long)blockIdx.x * blockDim.x + threadIdx.x;
    int e = (int)(t >> 5);
    if (e >= E) return;
    int j = ((int)t & 31) * 4;
    int r = rows[e]; int c = cols[e]; float v = vals[e];
    const float4 bv = *reinterpret_cast<const float4*>(b + (size_t)c * DIM + j);
    float* o = out + (size_t)r * DIM + j;
    atomicAdd(o + 0, v * bv.x);
    atomicAdd(o + 1, v * bv.y);
    atomicAdd(o + 2, v * bv.z);
    atomicAdd(o + 3, v * bv.w);
}

// ---------------- k1: coarse histogram ----------------
__global__ __launch_bounds__(256) void coarse_count_kernel(
    const int* __restrict__ rows, int* __restrict__ ccount, int E)
{
    __shared__ int hist[MAXNB];
    for (int i = threadIdx.x; i < MAXNB; i += 256) hist[i] = 0;
    __syncthreads();
    int chunk = (E + NCH - 1) / NCH;
    int s = blockIdx.x * chunk;
    int e = min(s + chunk, E);
    for (int i = s + threadIdx.x; i < e; i += 256)
        atomicAdd(&hist[rows[i] >> 5], 1);
    __syncthreads();
    for (int i = threadIdx.x; i < MAXNB; i += 256)
        if (hist[i]) atomicAdd(&ccount[i], hist[i]);
}

// ---------------- k2: exclusive scan, NB <= 4096, one block ----------------
__global__ __launch_bounds__(1024) void coarse_scan_kernel(
    const int* __restrict__ ccount, int* __restrict__ coffsets,
    int* __restrict__ ccursor, int NB, int E)
{
    __shared__ int s[1024];
    int t = threadIdx.x;
    int i0 = 4 * t;
    int a0 = (i0     < NB) ? ccount[i0]     : 0;
    int a1 = (i0 + 1 < NB) ? ccount[i0 + 1] : 0;
    int a2 = (i0 + 2 < NB) ? ccount[i0 + 2] : 0;
    int a3 = (i0 + 3 < NB) ? ccount[i0 + 3] : 0;
    int sum4 = a0 + a1 + a2 + a3;
    s[t] = sum4;
    __syncthreads();
    for (int off = 1; off < 1024; off <<= 1) {
        int x = (t >= off) ? s[t - off] : 0;
        __syncthreads();
        s[t] += x;
        __syncthreads();
    }
    int excl = s[t] - sum4;
    if (i0     < NB) { coffsets[i0]     = excl;                ccursor[i0]     = excl; }
    if (i0 + 1 < NB) { coffsets[i0 + 1] = excl + a0;           ccursor[i0 + 1] = excl + a0; }
    if (i0 + 2 < NB) { coffsets[i0 + 2] = excl + a0 + a1;      ccursor[i0 + 2] = excl + a0 + a1; }
    if (i0 + 3 < NB) { coffsets[i0 + 3] = excl + a0 + a1 + a2; ccursor[i0 + 3] = excl + a0 + a1 + a2; }
    if (t == 0) coffsets[NB] = E;
}

// ---------------- k3: 2-pass chunked partition ----------------
__global__ __launch_bounds__(256) void partition_kernel(
    const int* __restrict__ rows, const int* __restrict__ cols,
    const float* __restrict__ vals, int* __restrict__ ccursor,
    unsigned long long* __restrict__ pairs, int E)
{
    __shared__ int hist[MAXNB];
    __shared__ int base[MAXNB];
    for (int i = threadIdx.x; i < MAXNB; i += 256) hist[i] = 0;
    __syncthreads();
    int chunk = (E + NCH - 1) / NCH;
    int s = blockIdx.x * chunk;
    int e = min(s + chunk, E);
    for (int i = s + threadIdx.x; i < e; i += 256)
        atomicAdd(&hist[rows[i] >> 5], 1);
    __syncthreads();
    for (int i = threadIdx.x; i < MAXNB; i += 256) {
        int c = hist[i];
        base[i] = c ? atomicAdd(&ccursor[i], c) : 0;
        hist[i] = 0;                       // reuse as local rank cursor
    }
    __syncthreads();
    for (int i = s + threadIdx.x; i < e; i += 256) {
        int r = rows[i];
        int cb = r >> 5;
        int pos = base[cb] + atomicAdd(&hist[cb], 1);
        unsigned long long p =
            ((unsigned long long)(unsigned)__float_as_int(vals[i]) << 32) |
            (unsigned)((cols[i] << 5) | (r & (RPB - 1)));
        pairs[pos] = p;
    }
}

// ---------------- k4: sort (pad-to-8) + forced depth-2 pipeline ----------------
__global__ __launch_bounds__(BLK) void bucket_accum_kernel(
    const int* __restrict__ coffsets,
    const unsigned long long* __restrict__ pairs,
    const float* __restrict__ b, float* __restrict__ out, int N)
{
    __shared__ int2 svec[CAP];                 // {col*512, val_bits}; pads {0,0}
    __shared__ int fcnt[RPB];
    __shared__ int foff[RPB + 1];
    __shared__ int stmp[RPB];

    int cb = blockIdx.x;
    int cstart = coffsets[cb];
    int Mtot = coffsets[cb + 1] - cstart;
    int M = min(Mtot, STAGE);
    int t = threadIdx.x;

    // stage up to 6 pairs/thread into registers (static indexing)
    unsigned long long ep0 = 0, ep1 = 0, ep2 = 0, ep3 = 0, ep4 = 0, ep5 = 0;
    {
        const unsigned long long* p = pairs + cstart;
        if (t         < M) ep0 = p[t];
        if (t + 128   < M) ep1 = p[t + 128];
        if (t + 256   < M) ep2 = p[t + 256];
        if (t + 384   < M) ep3 = p[t + 384];
        if (t + 512   < M) ep4 = p[t + 512];
        if (t + 640   < M) ep5 = p[t + 640];
    }
    // zero svec (pads must be {0, 0.0}) + counters
    for (int i = t; i < CAP; i += BLK) svec[i] = make_int2(0, 0);
    if (t < RPB) fcnt[t] = 0;
    __syncthreads();

    // fine histogram
    if (t         < M) atomicAdd(&fcnt[(int)(ep0 & (RPB - 1))], 1);
    if (t + 128   < M) atomicAdd(&fcnt[(int)(ep1 & (RPB - 1))], 1);
    if (t + 256   < M) atomicAdd(&fcnt[(int)(ep2 & (RPB - 1))], 1);
    if (t + 384   < M) atomicAdd(&fcnt[(int)(ep3 & (RPB - 1))], 1);
    if (t + 512   < M) atomicAdd(&fcnt[(int)(ep4 & (RPB - 1))], 1);
    if (t + 640   < M) atomicAdd(&fcnt[(int)(ep5 & (RPB - 1))], 1);
    __syncthreads();

    // padded (to 8) inclusive scan of 32 counters
    int pc = 0;
    if (t < RPB) { pc = (fcnt[t] + 7) & ~7; stmp[t] = pc; }
    __syncthreads();
    for (int off = 1; off < RPB; off <<= 1) {
        int x = 0;
        if (t < RPB && t >= off) x = stmp[t - off];
        __syncthreads();
        if (t < RPB) stmp[t] += x;
        __syncthreads();
    }
    if (t < RPB) {
        int excl = stmp[t] - pc;
        foff[t] = excl;
        fcnt[t] = excl;                        // rank cursor (real entries)
    }
    if (t == RPB - 1) foff[RPB] = stmp[t];
    __syncthreads();

    // counting-sort write; pads stay {0, 0.0}
#define RANK_WRITE(EP, OFS)                                                  \
    if (t + (OFS) < M) {                                                     \
        unsigned lo = (unsigned)(EP & 0xffffffffu);                          \
        int pos = atomicAdd(&fcnt[(int)(lo & (RPB - 1))], 1);                \
        svec[pos] = make_int2((int)((lo & 0xffffffe0u) << 4),  /* col*512 */ \
                              (int)(EP >> 32));                              \
    }
    RANK_WRITE(ep0, 0)   RANK_WRITE(ep1, 128) RANK_WRITE(ep2, 256)
    RANK_WRITE(ep3, 384) RANK_WRITE(ep4, 512) RANK_WRITE(ep5, 640)
#undef RANK_WRITE
    __syncthreads();

    // wave-per-row accumulate: wave w owns rows [w*16, w*16+16)
    int wid  = t >> 6;                         // 0..1
    int lane = t & 63;
    const char* bl = (const char*)b + lane * 8;

    for (int j = 0; j < 16; ++j) {
        int rl = wid * 16 + j;
        int rg = cb * RPB + rl;
        if (rg >= N) break;                    // uniform within wave
        float2 acc = make_float2(0.f, 0.f);
        int ks = foff[rl], ke = foff[rl + 1];  // multiple-of-8 range
        if (ks < ke) {
            // preload group (8 edges)
            int2 e0 = svec[ks],     e1 = svec[ks + 1];
            int2 e2 = svec[ks + 2], e3 = svec[ks + 3];
            int2 e4 = svec[ks + 4], e5 = svec[ks + 5];
            int2 e6 = svec[ks + 6], e7 = svec[ks + 7];
            float2 c0 = *reinterpret_cast<const float2*>(bl + e0.x);
            float2 c1 = *reinterpret_cast<const float2*>(bl + e1.x);
            float2 c2 = *reinterpret_cast<const float2*>(bl + e2.x);
            float2 c3 = *reinterpret_cast<const float2*>(bl + e3.x);
            float2 c4 = *reinterpret_cast<const float2*>(bl + e4.x);
            float2 c5 = *reinterpret_cast<const float2*>(bl + e5.x);
            float2 c6 = *reinterpret_cast<const float2*>(bl + e6.x);
            float2 c7 = *reinterpret_cast<const float2*>(bl + e7.x);
            for (int k = ks + 8; k < ke; k += 8) {
                // issue next group's gathers FIRST...
                int2 f0 = svec[k],     f1 = svec[k + 1];
                int2 f2 = svec[k + 2], f3 = svec[k + 3];
                int2 f4 = svec[k + 4], f5 = svec[k + 5];
                int2 f6 = svec[k + 6], f7 = svec[k + 7];
                float2 d0 = *reinterpret_cast<const float2*>(bl + f0.x);
                float2 d1 = *reinterpret_cast<const float2*>(bl + f1.x);
                float2 d2 = *reinterpret_cast<const float2*>(bl + f2.x);
                float2 d3 = *reinterpret_cast<const float2*>(bl + f3.x);
                float2 d4 = *reinterpret_cast<const float2*>(bl + f4.x);
                float2 d5 = *reinterpret_cast<const float2*>(bl + f5.x);
                float2 d6 = *reinterpret_cast<const float2*>(bl + f6.x);
                float2 d7 = *reinterpret_cast<const float2*>(bl + f7.x);
                // ...and forbid the compiler from sinking them below the FMAs
                __builtin_amdgcn_sched_barrier(0);
                float v;
                v = __int_as_float(e0.y); acc.x = fmaf(v, c0.x, acc.x); acc.y = fmaf(v, c0.y, acc.y);
                v = __int_as_float(e1.y); acc.x = fmaf(v, c1.x, acc.x); acc.y = fmaf(v, c1.y, acc.y);
                v = __int_as_float(e2.y); acc.x = fmaf(v, c2.x, acc.x); acc.y = fmaf(v, c2.y, acc.y);
                v = __int_as_float(e3.y); acc.x = fmaf(v, c3.x, acc.x); acc.y = fmaf(v, c3.y, acc.y);
                v = __int_as_float(e4.y); acc.x = fmaf(v, c4.x, acc.x); acc.y = fmaf(v, c4.y, acc.y);
                v = __int_as_float(e5.y); acc.x = fmaf(v, c5.x, acc.x); acc.y = fmaf(v, c5.y, acc.y);
                v = __int_as_float(e6.y); acc.x = fmaf(v, c6.x, acc.x); acc.y = fmaf(v, c6.y, acc.y);
                v = __int_as_float(e7.y); acc.x = fmaf(v, c7.x, acc.x); acc.y = fmaf(v, c7.y, acc.y);
                e0 = f0; e1 = f1; e2 = f2; e3 = f3;
                e4 = f4; e5 = f5; e6 = f6; e7 = f7;
                c0 = d0; c1 = d1; c2 = d2; c3 = d3;
                c4 = d4; c5 = d5; c6 = d6; c7 = d7;
            }
            float v;
            v = __int_as_float(e0.y); acc.x = fmaf(v, c0.x, acc.x); acc.y = fmaf(v, c0.y, acc.y);
            v = __int_as_float(e1.y); acc.x = fmaf(v, c1.x, acc.x); acc.y = fmaf(v, c1.y, acc.y);
            v = __int_as_float(e2.y); acc.x = fmaf(v, c2.x, acc.x); acc.y = fmaf(v, c2.y, acc.y);
            v = __int_as_float(e3.y); acc.x = fmaf(v, c3.x, acc.x); acc.y = fmaf(v, c3.y, acc.y);
            v = __int_as_float(e4.y); acc.x = fmaf(v, c4.x, acc.x); acc.y = fmaf(v, c4.y, acc.y);
            v = __int_as_float(e5.y); acc.x = fmaf(v, c5.x, acc.x); acc.y = fmaf(v, c5.y, acc.y);
            v = __int_as_float(e6.y); acc.x = fmaf(v, c6.x, acc.x); acc.y = fmaf(v, c6.y, acc.y);
            v = __int_as_float(e7.y); acc.x = fmaf(v, c7.x, acc.x); acc.y = fmaf(v, c7.y, acc.y);
        }
        // overflow edges beyond STAGE (statistically never; correctness path)
        for (int q = STAGE; q < Mtot; ++q) {
            unsigned long long p = pairs[cstart + q];
            if ((int)(p & (RPB - 1)) == rl) {
                unsigned lo = (unsigned)(p & 0xffffffffu);
                float v = __int_as_float((int)(p >> 32));
                float2 bv = *reinterpret_cast<const float2*>(
                    bl + (int)((lo & 0xffffffe0u) << 4));
                acc.x = fmaf(v, bv.x, acc.x);  acc.y = fmaf(v, bv.y, acc.y);
            }
        }
        *reinterpret_cast<float2*>(out + (size_t)rg * DIM + lane * 2) = acc;
    }
}

extern "C" void kernel_launch(void* const* d_in, const int* in_sizes, int n_in,
                              void* d_out, int out_size, void* d_ws, size_t ws_size,
                              hipStream_t stream)
{
    const int*   indices = (const int*)d_in[0];    // [2, E]: rows then cols
    const float* vals    = (const float*)d_in[1];  // [E]
    const float* b       = (const float*)d_in[2];  // [N, 128]
    float*       out     = (float*)d_out;          // [N, 128]

    const int E = in_sizes[1];
    const int N = in_sizes[2] / DIM;
    const int* rows = indices;
    const int* cols = indices + E;

    const int NB = (N + RPB - 1) / RPB;            // buckets

    size_t pairs_bytes = (size_t)E * 8;
    size_t needed = pairs_bytes + ((size_t)NB * 3 + 1) * 4;

    if (ws_size < needed || NB > MAXNB || NB < 1 || E < 1) {
        hipMemsetAsync(d_out, 0, (size_t)out_size * sizeof(float), stream);
        if (E >= 1) {
            const long long total = (long long)E * 32;
            const int grid = (int)((total + 255) / 256);
            spmm_atomic_kernel<<<grid, 256, 0, stream>>>(rows, cols, vals, b, out, E);
        }
        return;
    }

    unsigned long long* pairs = (unsigned long long*)d_ws;
    int* ccount   = (int*)((char*)d_ws + pairs_bytes);
    int* coffsets = ccount + NB;
    int* ccursor  = coffsets + (NB + 1);

    hipMemsetAsync(ccount, 0, (size_t)NB * sizeof(int), stream);
    coarse_count_kernel<<<NCH, 256, 0, stream>>>(rows, ccount, E);
    coarse_scan_kernel<<<1, 1024, 0, stream>>>(ccount, coffsets, ccursor, NB, E);
    partition_kernel<<<NCH, 256, 0, stream>>>(rows, cols, vals, ccursor, pairs, E);
    bucket_accum_kernel<<<NB, BLK, 0, stream>>>(coffsets, pairs, b, out, N);
}